// Round 3
// baseline (1881.370 us; speedup 1.0000x reference)
//
#include <hip/hip_runtime.h>
#include <math.h>

// Problem constants
constexpr int Bq = 128;   // batch
constexpr int Nn = 512;   // nodes
constexpr int Dd = 300;   // feature dim
constexpr int Aa = 32;    // attention dim
constexpr int DT = 304;   // d padded to 19 tiles of 16 for MFMA N-dim

typedef __attribute__((ext_vector_type(8))) short short8;   // 8 bf16 (4 VGPRs)
typedef __attribute__((ext_vector_type(4))) float float4v;  // MFMA acc

static __device__ __forceinline__ ushort f2bf(float x) {
    unsigned u = __float_as_uint(x);
    return (ushort)((u + 0x7FFF + ((u >> 16) & 1)) >> 16);   // RNE
}

// ---------------- Kernel 1: Q/K projection + bf16 X^T emission ----------------
constexpr int KB_ROWS = 128;
constexpr int DCHUNK = 100;      // 300 = 3 x 100
constexpr int XS_STRIDE = 102;   // even: float2-aligned rows; r-read banks spread

__global__ __launch_bounds__(256) void proj_qk(
    const float* __restrict__ X, const float* __restrict__ Wq,
    const float* __restrict__ Wk, float* __restrict__ Qo, float* __restrict__ Ko,
    ushort* __restrict__ XbfT)
{
    __shared__ float xs[KB_ROWS * XS_STRIDE];  // ~51 KB
    const int b  = blockIdx.y;
    const int n0 = blockIdx.x * KB_ROWS;
    const int t  = threadIdx.x;
    const int c  = t & 15;
    const int r  = t >> 4;
    const int a4 = c * 4;
    const int rbase = r * 8;
    const float* Wbase = (a4 < Aa) ? (Wq + a4) : (Wk + (a4 - Aa));
    const float* Xb = X + ((size_t)(b * Nn + n0)) * Dd;

    float4 acc[8];
#pragma unroll
    for (int j = 0; j < 8; ++j) acc[j] = make_float4(0.f, 0.f, 0.f, 0.f);

    for (int d0 = 0; d0 < Dd; d0 += DCHUNK) {
        // stage X chunk [128 rows x 100 d] as float2
        for (int l = t; l < KB_ROWS * (DCHUNK / 2); l += 256) {
            int row = l / (DCHUNK / 2);
            int dd2 = l - row * (DCHUNK / 2);
            *(float2*)(xs + row * XS_STRIDE + dd2 * 2) =
                *(const float2*)(Xb + (size_t)row * Dd + d0 + dd2 * 2);
        }
        __syncthreads();
        for (int dd = 0; dd < DCHUNK; ++dd) {
            float4 w4 = *(const float4*)(Wbase + (size_t)(d0 + dd) * Aa);
#pragma unroll
            for (int j = 0; j < 8; ++j) {
                float xv = xs[(rbase + j) * XS_STRIDE + dd];
                acc[j].x += xv * w4.x; acc[j].y += xv * w4.y;
                acc[j].z += xv * w4.z; acc[j].w += xv * w4.w;
            }
        }
        // emit bf16 transposed chunk: XbfT[b][d0+dd][n0+row]
        for (int l = t; l < KB_ROWS * DCHUNK; l += 256) {
            int dd  = l >> 7;        // 12800 = 100 x 128
            int row = l & 127;
            XbfT[((size_t)b * DT + d0 + dd) * Nn + n0 + row] =
                f2bf(xs[row * XS_STRIDE + dd]);
        }
        __syncthreads();
    }

    float* Obase = (a4 < Aa) ? (Qo + a4) : (Ko + (a4 - Aa));
#pragma unroll
    for (int j = 0; j < 8; ++j) {
        int n = n0 + rbase + j;
        *(float4*)(Obase + (size_t)(b * Nn + n) * Aa) = acc[j];
    }
}

// ---------------- Kernel 2: fused scores + softmax + MFMA aggregation ----------------
// One block per (b, 32-row n tile). 256 threads (4 waves).
constexpr int TN = 32;   // rows per block = two 16-row MFMA row-sets

__global__ __launch_bounds__(256, 2) void attn_kernel(
    const float* __restrict__ Adj, const float* __restrict__ Q,
    const float* __restrict__ K, const ushort* __restrict__ XbfT,
    float* __restrict__ Out)
{
    __shared__ float qs[TN * Aa];                            // 4 KB
    __shared__ __align__(16) ushort fragA[2 * 16 * 64 * 8];  // 32 KB: 2 row-sets, frag-packed
    __shared__ float redbuf[4 * TN];                         // 512 B
    __shared__ float rowstat[TN];                            // 1/denominator

    const int b    = blockIdx.y;
    const int n0   = blockIdx.x * TN;
    const int t    = threadIdx.x;
    const int lane = t & 63;
    const int wv   = t >> 6;

    for (int l = t; l < TN * Aa; l += 256)
        qs[l] = Q[((size_t)(b * Nn + n0)) * Aa + l];
    __syncthreads();

    // ---- Phase 1: e = exp(QK * adj); frag-packed bf16 store; running row sums ----
    float psum[TN];
#pragma unroll
    for (int i = 0; i < TN; ++i) psum[i] = 0.f;

    for (int c = 0; c < 2; ++c) {
        const int m = c * 256 + t;
        float4 kv[8];
        const float4* kp = (const float4*)(K + ((size_t)(b * Nn + m)) * Aa);
#pragma unroll
        for (int j = 0; j < 8; ++j) kv[j] = kp[j];

        const float* adjCol = Adj + ((size_t)(b * Nn + n0)) * Nn + m;
        const int ks = m >> 5, q = (m >> 3) & 3, jj = m & 7;
        // unit = ks*64 + q*16 + (i&15); elem = unit*8 + jj; set (i>>4) adds 8192
        ushort* wp = fragA + ((ks * 64 + q * 16) * 8 + jj);

#pragma unroll
        for (int i = 0; i < TN; ++i) {
            const float4* q4 = (const float4*)(qs + i * Aa);
            float d = 0.f;
#pragma unroll
            for (int j = 0; j < 8; ++j) {
                float4 qv = q4[j];
                d += qv.x * kv[j].x + qv.y * kv[j].y + qv.z * kv[j].z + qv.w * kv[j].w;
            }
            float a = adjCol[(size_t)i * Nn];
            float e = __expf(d * a);          // a==0 -> e=1 exactly, as reference
            psum[i] += e;
            wp[(i >> 4) * 8192 + (i & 15) * 8] = f2bf(e);
        }
    }

    // ---- Phase 2: denominator reduction (no max pass: |scores| small) ----
#pragma unroll
    for (int i = 0; i < TN; ++i) {
        float v = psum[i];
#pragma unroll
        for (int off = 32; off > 0; off >>= 1) v += __shfl_down(v, off);
        if (lane == 0) redbuf[wv * TN + i] = v;
    }
    __syncthreads();
    if (t < TN)
        rowstat[t] = 1.0f / (redbuf[t] + redbuf[TN + t] + redbuf[2 * TN + t] + redbuf[3 * TN + t]);
    __syncthreads();

    // ---- Phase 3: Out[i][d] = inv[i] * sum_m e[i][m] * X[m][d] via MFMA ----
    const int qd = lane >> 4;
    const int dl = lane & 15;
    float inv0[4], inv1[4];
#pragma unroll
    for (int r = 0; r < 4; ++r) {
        inv0[r] = rowstat[qd * 4 + r];
        inv1[r] = rowstat[16 + qd * 4 + r];
    }

    const ushort* Xb = XbfT + ((size_t)b * DT) * Nn;
    const ushort* afp = fragA + (size_t)lane * 8;
    for (int dt = wv; dt < DT / 16; dt += 4) {
        const int d = dt * 16 + dl;
        const ushort* bb = Xb + (size_t)d * Nn + qd * 8;
        float4v acc0 = {0.f, 0.f, 0.f, 0.f};
        float4v acc1 = {0.f, 0.f, 0.f, 0.f};
#pragma unroll
        for (int ks = 0; ks < 16; ++ks) {
            short8 bf = *(const short8*)(bb + ks * 32);
            short8 a0 = *(const short8*)(afp + ks * 512);
            short8 a1 = *(const short8*)(afp + 8192 + ks * 512);
            acc0 = __builtin_amdgcn_mfma_f32_16x16x32_bf16(a0, bf, acc0, 0, 0, 0);
            acc1 = __builtin_amdgcn_mfma_f32_16x16x32_bf16(a1, bf, acc1, 0, 0, 0);
        }
        if (d < Dd) {
#pragma unroll
            for (int r = 0; r < 4; ++r) {
                Out[((size_t)(b * Nn + n0 + qd * 4 + r)) * Dd + d]      = acc0[r] * inv0[r];
                Out[((size_t)(b * Nn + n0 + 16 + qd * 4 + r)) * Dd + d] = acc1[r] * inv1[r];
            }
        }
    }
}

// ---------------- launch ----------------
extern "C" void kernel_launch(void* const* d_in, const int* in_sizes, int n_in,
                              void* d_out, int out_size, void* d_ws, size_t ws_size,
                              hipStream_t stream) {
    const float* X   = (const float*)d_in[0];   // [128,512,300]
    const float* Adj = (const float*)d_in[1];   // [128,512,512]
    const float* Wq  = (const float*)d_in[2];   // [300,32]
    const float* Wk  = (const float*)d_in[3];   // [300,32]
    float* Out = (float*)d_out;                 // [128,512,300]

    float*  Qw   = (float*)d_ws;                                      // 8 MB
    float*  Kw   = Qw + (size_t)Bq * Nn * Aa;                         // 8 MB
    ushort* XbfT = (ushort*)((char*)d_ws + (size_t)32 * 1024 * 1024); // ~39.9 MB

    proj_qk<<<dim3(Nn / KB_ROWS, Bq), 256, 0, stream>>>(X, Wq, Wk, Qw, Kw, XbfT);
    attn_kernel<<<dim3(Nn / TN, Bq), 256, 0, stream>>>(Adj, Qw, Kw, XbfT, Out);
}

// Round 4
// 407.179 us; speedup vs baseline: 4.6205x; 4.6205x over previous
//
#include <hip/hip_runtime.h>
#include <math.h>

// Problem constants
constexpr int Bq = 128;   // batch
constexpr int Nn = 512;   // nodes
constexpr int Dd = 300;   // feature dim
constexpr int Aa = 32;    // attention dim
constexpr int DT = 304;   // d padded to 19 tiles of 16 for MFMA N-dim

typedef __attribute__((ext_vector_type(8))) short short8;   // 8 bf16 (4 VGPRs)
typedef __attribute__((ext_vector_type(4))) float float4v;  // MFMA acc

static __device__ __forceinline__ ushort f2bf(float x) {
    unsigned u = __float_as_uint(x);
    return (ushort)((u + 0x7FFF + ((u >> 16) & 1)) >> 16);   // RNE
}

// ---------------- Kernel 1: Q/K projection (bf16 out) + bf16 X^T emission ----------------
constexpr int KB_ROWS = 128;
constexpr int DCHUNK = 100;      // 300 = 3 x 100
constexpr int XS_STRIDE = 102;

__global__ __launch_bounds__(256) void proj_qk(
    const float* __restrict__ X, const float* __restrict__ Wq,
    const float* __restrict__ Wk, ushort* __restrict__ Qo, ushort* __restrict__ Ko,
    ushort* __restrict__ XbfT)
{
    __shared__ float xs[KB_ROWS * XS_STRIDE];  // ~51 KB
    const int b  = blockIdx.y;
    const int n0 = blockIdx.x * KB_ROWS;
    const int t  = threadIdx.x;
    const int c  = t & 15;
    const int r  = t >> 4;
    const int a4 = c * 4;
    const int rbase = r * 8;
    const float* Wbase = (a4 < Aa) ? (Wq + a4) : (Wk + (a4 - Aa));
    const float* Xb = X + ((size_t)(b * Nn + n0)) * Dd;

    float4 acc[8];
#pragma unroll
    for (int j = 0; j < 8; ++j) acc[j] = make_float4(0.f, 0.f, 0.f, 0.f);

    for (int d0 = 0; d0 < Dd; d0 += DCHUNK) {
        for (int l = t; l < KB_ROWS * (DCHUNK / 2); l += 256) {
            int row = l / (DCHUNK / 2);
            int dd2 = l - row * (DCHUNK / 2);
            *(float2*)(xs + row * XS_STRIDE + dd2 * 2) =
                *(const float2*)(Xb + (size_t)row * Dd + d0 + dd2 * 2);
        }
        __syncthreads();
        for (int dd = 0; dd < DCHUNK; ++dd) {
            float4 w4 = *(const float4*)(Wbase + (size_t)(d0 + dd) * Aa);
#pragma unroll
            for (int j = 0; j < 8; ++j) {
                float xv = xs[(rbase + j) * XS_STRIDE + dd];
                acc[j].x += xv * w4.x; acc[j].y += xv * w4.y;
                acc[j].z += xv * w4.z; acc[j].w += xv * w4.w;
            }
        }
        // emit bf16 transposed chunk: XbfT[b][d0+dd][n0+row]
        for (int l = t; l < KB_ROWS * DCHUNK; l += 256) {
            int dd  = l >> 7;        // 12800 = 100 x 128
            int row = l & 127;
            XbfT[((size_t)b * DT + d0 + dd) * Nn + n0 + row] =
                f2bf(xs[row * XS_STRIDE + dd]);
        }
        __syncthreads();
    }

    ushort* Obase = (a4 < Aa) ? (Qo + a4) : (Ko + (a4 - Aa));
#pragma unroll
    for (int j = 0; j < 8; ++j) {
        int n = n0 + rbase + j;
        ushort4 o;
        o.x = f2bf(acc[j].x); o.y = f2bf(acc[j].y);
        o.z = f2bf(acc[j].z); o.w = f2bf(acc[j].w);
        *(ushort4*)(Obase + (size_t)(b * Nn + n) * Aa) = o;
    }
}

// ---------------- Kernel 2: all-MFMA scores + softmax + MFMA aggregation ----------------
// One block per (b, 32-row tile). 256 threads. XCD-swizzled 1-D grid.
constexpr int TN = 32;

__global__ __launch_bounds__(256, 2) void attn_kernel(
    const float* __restrict__ Adj, const ushort* __restrict__ Qbf,
    const ushort* __restrict__ Kbf, const ushort* __restrict__ XbfT,
    float* __restrict__ Out)
{
    __shared__ __align__(16) ushort fragA[2 * 8192];   // 32 KB, frag-packed e values
    __shared__ float wsum[4][TN];
    __shared__ float rowstat[TN];                      // 1/denominator

    // XCD swizzle: each XCD (blk%8) streams all 16 tiles of one batch consecutively
    const int blk  = blockIdx.x;
    const int b    = ((blk >> 7) << 3) | (blk & 7);
    const int n0   = ((blk >> 3) & 15) * TN;

    const int t    = threadIdx.x;
    const int lane = t & 63;
    const int wv   = t >> 6;
    const int dl   = lane & 15;
    const int quad = lane >> 4;

    // ---- Phase 1: S = Q K^T via MFMA; e = exp(S*adj) -> fragA (bf16) ----
    short8 qfr[2];
#pragma unroll
    for (int rs = 0; rs < 2; ++rs)
        qfr[rs] = *(const short8*)(Qbf + ((size_t)(b * Nn + n0 + rs * 16 + dl)) * Aa + quad * 8);

    float dsum[2][4];
#pragma unroll
    for (int rs = 0; rs < 2; ++rs)
#pragma unroll
        for (int r = 0; r < 4; ++r) dsum[rs][r] = 0.f;

    const float* adjB = Adj + (size_t)b * Nn * Nn;

    for (int ks = wv; ks < 16; ks += 4) {
        const int m0 = ks * 32;
        short8 kf0 = *(const short8*)(Kbf + ((size_t)(b * Nn + m0 + dl)) * Aa + quad * 8);
        short8 kf1 = *(const short8*)(Kbf + ((size_t)(b * Nn + m0 + 16 + dl)) * Aa + quad * 8);
        // writer target: elem = rs*8192 + (ks*64 + q2*16 + ii)*8 + jj
        //   kf0 half: k_local = dl      -> q2 = dl>>3,     jj = dl&7
        //   kf1 half: k_local = 16 + dl -> q2 = 2 + (dl>>3) -> +256 elems
        ushort* wp = fragA + ks * 512 + (dl >> 3) * 128 + (dl & 7);
#pragma unroll
        for (int rs = 0; rs < 2; ++rs) {
            float4v z = {0.f, 0.f, 0.f, 0.f};
            float4v acc0 = __builtin_amdgcn_mfma_f32_16x16x32_bf16(qfr[rs], kf0, z, 0, 0, 0);
            float4v acc1 = __builtin_amdgcn_mfma_f32_16x16x32_bf16(qfr[rs], kf1, z, 0, 0, 0);
            const float* ap = adjB + (size_t)(n0 + rs * 16 + quad * 4) * Nn + m0 + dl;
            ushort* wpr = wp + rs * 8192;
#pragma unroll
            for (int r = 0; r < 4; ++r) {
                float a0 = ap[(size_t)r * Nn];
                float a1 = ap[(size_t)r * Nn + 16];
                float e0 = __expf(acc0[r] * a0);    // adj==0 -> e=1 exactly
                float e1 = __expf(acc1[r] * a1);
                dsum[rs][r] += e0 + e1;
                ushort* w2 = wpr + (quad * 4 + r) * 8;
                w2[0]   = f2bf(e0);
                w2[256] = f2bf(e1);
            }
        }
    }

    // ---- Phase 2: denominators (no max pass: |scores| tiny) ----
#pragma unroll
    for (int rs = 0; rs < 2; ++rs)
#pragma unroll
        for (int r = 0; r < 4; ++r) {
            float v = dsum[rs][r];
            v += __shfl_xor(v, 1);
            v += __shfl_xor(v, 2);
            v += __shfl_xor(v, 4);
            v += __shfl_xor(v, 8);
            if (dl == 0) wsum[wv][rs * 16 + quad * 4 + r] = v;
        }
    __syncthreads();
    if (t < TN)
        rowstat[t] = 1.0f / (wsum[0][t] + wsum[1][t] + wsum[2][t] + wsum[3][t]);
    __syncthreads();

    // ---- Phase 3: Out[i][d] = inv[i] * sum_m e[i][m] * X[m][d] via MFMA ----
    float inv0[4], inv1[4];
#pragma unroll
    for (int r = 0; r < 4; ++r) {
        inv0[r] = rowstat[quad * 4 + r];
        inv1[r] = rowstat[16 + quad * 4 + r];
    }

    const ushort* Xb  = XbfT + ((size_t)b * DT) * Nn;
    const ushort* afp = fragA + (size_t)lane * 8;
    for (int dt = wv; dt < DT / 16; dt += 4) {
        const int d = dt * 16 + dl;
        const ushort* bb = Xb + (size_t)d * Nn + quad * 8;
        float4v acc0 = {0.f, 0.f, 0.f, 0.f};
        float4v acc1 = {0.f, 0.f, 0.f, 0.f};
#pragma unroll
        for (int ks = 0; ks < 16; ++ks) {
            short8 bf = *(const short8*)(bb + ks * 32);
            short8 a0 = *(const short8*)(afp + ks * 512);
            short8 a1 = *(const short8*)(afp + 8192 + ks * 512);
            acc0 = __builtin_amdgcn_mfma_f32_16x16x32_bf16(a0, bf, acc0, 0, 0, 0);
            acc1 = __builtin_amdgcn_mfma_f32_16x16x32_bf16(a1, bf, acc1, 0, 0, 0);
        }
        if (d < Dd) {
#pragma unroll
            for (int r = 0; r < 4; ++r) {
                Out[((size_t)(b * Nn + n0 + quad * 4 + r)) * Dd + d]      = acc0[r] * inv0[r];
                Out[((size_t)(b * Nn + n0 + 16 + quad * 4 + r)) * Dd + d] = acc1[r] * inv1[r];
            }
        }
    }
}

// ---------------- launch ----------------
extern "C" void kernel_launch(void* const* d_in, const int* in_sizes, int n_in,
                              void* d_out, int out_size, void* d_ws, size_t ws_size,
                              hipStream_t stream) {
    const float* X   = (const float*)d_in[0];   // [128,512,300]
    const float* Adj = (const float*)d_in[1];   // [128,512,512]
    const float* Wq  = (const float*)d_in[2];   // [300,32]
    const float* Wk  = (const float*)d_in[3];   // [300,32]
    float* Out = (float*)d_out;                 // [128,512,300]

    ushort* Qbf  = (ushort*)d_ws;                                      // 4 MB
    ushort* Kbf  = (ushort*)((char*)d_ws + (size_t)4 * 1024 * 1024);   // 4 MB
    ushort* XbfT = (ushort*)((char*)d_ws + (size_t)8 * 1024 * 1024);   // ~39.9 MB

    proj_qk<<<dim3(Nn / KB_ROWS, Bq), 256, 0, stream>>>(X, Wq, Wk, Qbf, Kbf, XbfT);
    attn_kernel<<<dim3(Bq * Nn / TN), 256, 0, stream>>>(Adj, Qbf, Kbf, XbfT, Out);
}